// Round 6
// baseline (63.494 us; speedup 1.0000x reference)
//
#include <hip/hip_runtime.h>
#include <hip/hip_bf16.h>

// loss = mean((output-target)^2) + ALPHA * sum(masked cosine Gram of
// V[128][196608]), V[f][d] = conv_w[o][i][f][k], d=(site,k), site=(o,i).
//
// Round 6: DMA-staged fused kernel. global_load_lds (16B) double-buffered
// half-chunks (16 sites, 24 KB) -> convert to bf16 tile (K=96) -> MFMA every
// 2 halves. 512 blocks, 2 blocks/CU (75.8 KB LDS), counted vmcnt so DMA and
// MSE loads stay in flight across barriers. MSE interleaved (2 f4-pairs per
// half, consumed one half later). Partials stored as bf16 pairs (16.8 MB).

typedef __attribute__((ext_vector_type(8))) short bf16x8;   // 8 bf16 = 4 VGPR
typedef __attribute__((ext_vector_type(4))) float f32x4;

#define ALPHA 0.0005f
#define TAU 0.2f

#define FDIM 128
#define TSTRIDE 52          // tile row stride in dwords (48 data + 4 pad)
#define NBLK 512
#define NHALF 8             // half-chunks per block (16 sites each)
#define HALF_F 6144         // floats per half-chunk (16 sites * 384)
#define GRAM_ELEMS 16384
#define NPAIRQ 8192         // packed u32 per partial tile
#define MSE_STRIDE 131072   // 512 blk * 256 thr
#define MSE_N4 2048000

#define AS1 __attribute__((address_space(1)))
#define AS3 __attribute__((address_space(3)))

__device__ __forceinline__ void issue6(const float* g, float* l, int tid, int wave) {
#pragma unroll
    for (int it = 0; it < 6; ++it)
        __builtin_amdgcn_global_load_lds((AS1 const void*)(g + (it * 256 + tid) * 4),
                                         (AS3 void*)(l + (it * 256 + wave * 64) * 4),
                                         16, 0, 0);
}

// branchless RNE f32->bf16 pair pack
__device__ __forceinline__ unsigned int pack_bf2(float lo, float hi) {
    union { float f; unsigned int u; } a, b;
    a.f = lo; b.f = hi;
    unsigned int al = (a.u + 0x7fffu + ((a.u >> 16) & 1u)) >> 16;
    unsigned int bh = (b.u + 0x7fffu + ((b.u >> 16) & 1u)) & 0xffff0000u;
    return (al & 0xffffu) | bh;
}

__device__ __forceinline__ void mse_acc(const f32x4 (&M)[4], float& s) {
    f32x4 d0 = M[0] - M[1];
    f32x4 d1 = M[2] - M[3];
    s += d0[0]*d0[0] + d0[1]*d0[1] + d0[2]*d0[2] + d0[3]*d0[3]
       + d1[0]*d1[0] + d1[1]*d1[1] + d1[2]*d1[2] + d1[3]*d1[3];
}

__device__ __forceinline__ void hard_barrier() {
    asm volatile("s_waitcnt lgkmcnt(0)" ::: "memory");
    __builtin_amdgcn_sched_barrier(0);
    __builtin_amdgcn_s_barrier();
    __builtin_amdgcn_sched_barrier(0);
}

// convert one 16-site half from raw fp32 LDS into the bf16 tile.
// tile dword [f][k*16 + ch*8 + p] = pack(site 2p, site 2p+1), p in [0,8).
__device__ __forceinline__ void convert_half(const float* rawbuf,
                                             unsigned int* tile,
                                             int p, int q, int ch) {
    const f32x4* rr = reinterpret_cast<const f32x4*>(rawbuf);
#pragma unroll
    for (int it = 0; it < 3; ++it) {
        f32x4 v0 = rr[(2 * p) * 96 + q + 32 * it];
        f32x4 v1 = rr[(2 * p + 1) * 96 + q + 32 * it];
#pragma unroll
        for (int u = 0; u < 4; ++u) {
            const int idx = (q + 32 * it) * 4 + u;  // [0,384): f*3 + k
            const int f = idx / 3;                  // magic-mul
            const int k = idx - 3 * f;
            tile[f * TSTRIDE + k * 16 + ch * 8 + p] = pack_bf2(v0[u], v1[u]);
        }
    }
}

__device__ __forceinline__ void mfmaph(const unsigned short* __restrict__ tu,
                                       int wave, int colr, int hi8,
                                       f32x4 (&acc0)[8], f32x4 (&acc1)[8]) {
#pragma unroll
    for (int ks = 0; ks < 3; ++ks) {
        const int koff = ks * 32 + hi8;
        bf16x8 a0 = *reinterpret_cast<const bf16x8*>(
            &tu[(wave * 32 + colr) * (TSTRIDE * 2) + koff]);
        bf16x8 a1 = *reinterpret_cast<const bf16x8*>(
            &tu[(wave * 32 + 16 + colr) * (TSTRIDE * 2) + koff]);
#pragma unroll
        for (int cc = 0; cc < 8; ++cc) {
            bf16x8 b = *reinterpret_cast<const bf16x8*>(
                &tu[(cc * 16 + colr) * (TSTRIDE * 2) + koff]);
            acc0[cc] = __builtin_amdgcn_mfma_f32_16x16x32_bf16(a0, b, acc0[cc], 0, 0, 0);
            acc1[cc] = __builtin_amdgcn_mfma_f32_16x16x32_bf16(a1, b, acc1[cc], 0, 0, 0);
        }
    }
}

// ------------------------------------------------- fused MSE + Gram kernel
__global__ void __launch_bounds__(256, 2) fused_kernel(
        const float* __restrict__ o, const float* __restrict__ t,
        const float* __restrict__ conv,
        float* __restrict__ mse_part, unsigned int* __restrict__ pp) {
    __shared__ float raw[2][HALF_F];                    // 48 KB
    __shared__ unsigned int tile[FDIM * TSTRIDE];       // 26.6 KB
    __shared__ float red[4];
    const int tid = threadIdx.x;
    const int lane = tid & 63;
    const int wave = tid >> 6;
    const int p = tid >> 5;                 // site pair within half, 0..7
    const int q = tid & 31;                 // float4 sub-offset, 0..31
    const int colr = lane & 15;
    const int hi8 = (lane >> 4) * 8;
    const int gid = blockIdx.x * 256 + tid;
    const bool tail_ok = blockIdx.x < (MSE_N4 - 15 * MSE_STRIDE) / 256;  // 320
    const float* base = conv + (size_t)blockIdx.x * (NHALF * HALF_F);
    const f32x4* o4 = reinterpret_cast<const f32x4*>(o);
    const f32x4* t4 = reinterpret_cast<const f32x4*>(t);
    const unsigned short* tileu = reinterpret_cast<const unsigned short*>(tile);

    f32x4 acc0[8], acc1[8];
#pragma unroll
    for (int cc = 0; cc < 8; ++cc) { acc0[cc] = (f32x4)0.f; acc1[cc] = (f32x4)0.f; }
    float msum = 0.f;
    f32x4 Ma[4], Mb[4];

    issue6(base, &raw[0][0], tid, wave);    // DMA half 0

#pragma unroll
    for (int h = 0; h < NHALF; ++h) {
        const int cur = h & 1;
        if (h + 1 < NHALF)
            issue6(base + (h + 1) * HALF_F, &raw[cur ^ 1][0], tid, wave);
        // mse loads: pairs 2h, 2h+1 (pair 15 masked on blocks >= 320)
        {
            const int i0 = gid + (2 * h) * MSE_STRIDE;
            const int i1 = gid + (2 * h + 1) * MSE_STRIDE;
            const bool ok1 = (h < NHALF - 1) || tail_ok;
            if (cur == 0) {
                Ma[0] = o4[i0]; Ma[1] = t4[i0];
                Ma[2] = ok1 ? o4[i1] : (f32x4)0.f;
                Ma[3] = ok1 ? t4[i1] : (f32x4)0.f;
            } else {
                Mb[0] = o4[i0]; Mb[1] = t4[i0];
                Mb[2] = ok1 ? o4[i1] : (f32x4)0.f;
                Mb[3] = ok1 ? t4[i1] : (f32x4)0.f;
            }
        }
        // consume previous half's mse registers (one half-period of latency)
        if (h > 0) { if (cur == 0) mse_acc(Mb, msum); else mse_acc(Ma, msum); }
        // wait raw[cur] DMA (FIFO: 6 gl_lds + 4 mse loads newer), keep rest in flight
        if (h + 1 < NHALF) asm volatile("s_waitcnt vmcnt(10)" ::: "memory");
        else               asm volatile("s_waitcnt vmcnt(4)"  ::: "memory");
        hard_barrier();                     // raw[cur] ready; tile consumed
        convert_half(&raw[cur][0], tile, p, q, cur);
        if (cur == 1) {
            hard_barrier();                 // full K=96 tile ready
            mfmaph(tileu, wave, colr, hi8, acc0, acc1);
        }
    }
    mse_acc(Mb, msum);                      // pairs 14,15 (loaded at h=7)

    // mse block reduction
    for (int off = 32; off; off >>= 1) msum += __shfl_down(msum, off);
    if (lane == 0) red[wave] = msum;
    __syncthreads();
    if (tid == 0) mse_part[blockIdx.x] = red[0] + red[1] + red[2] + red[3];

    // partial tile, bf16 pair-packed: u32[pr*128+col] = pack(G[r], G[r+16]),
    // r = (pr>>4)*32 + (pr&15)
    unsigned int* myp = pp + (size_t)blockIdx.x * NPAIRQ;
    const int rsub = (lane >> 4) << 2;
#pragma unroll
    for (int cc = 0; cc < 8; ++cc) {
        const int col = cc * 16 + colr;
#pragma unroll
        for (int j = 0; j < 4; ++j) {
            const int pr = wave * 16 + rsub + j;
            myp[pr * FDIM + col] = pack_bf2(acc0[cc][j], acc1[cc][j]);
        }
    }
}

// ------------------------------------------------- partial reduce (bf16 pairs)
// 512 blocks x 256 thr: block owns 16 packed columns; 16 slices of 32 tiles.
__global__ void __launch_bounds__(256) reduce_kernel(
        const unsigned int* __restrict__ pp, float* __restrict__ gram) {
    __shared__ float red[16][16][2];
    const int tid = threadIdx.x;
    const int u = tid & 15;
    const int s = tid >> 4;                 // 0..15
    const int qq = blockIdx.x * 16 + u;
    float lo = 0.f, hi = 0.f;
#pragma unroll 8
    for (int b = s * 32; b < s * 32 + 32; ++b) {
        const unsigned int v = pp[(size_t)b * NPAIRQ + qq];
        lo += __uint_as_float(v << 16);
        hi += __uint_as_float(v & 0xffff0000u);
    }
    red[s][u][0] = lo; red[s][u][1] = hi;
    __syncthreads();
    if (tid < 32) {
        const int u2 = tid >> 1, h = tid & 1;
        float x = 0.f;
#pragma unroll
        for (int s2 = 0; s2 < 16; ++s2) x += red[s2][u2][h];
        gram[(blockIdx.x * 16 + u2) * 2 + h] = x;
    }
}

// ------------------------------------------------------------ finalize
// gram layout: g = (pr*128+col)*2 + h, row = (pr>>4)*32 + (pr&15) + 16h
__global__ void __launch_bounds__(256) finalize_kernel(
        const float* __restrict__ gram, const float* __restrict__ mse_part,
        float* __restrict__ out) {
    __shared__ float rn[FDIM];
    __shared__ float redS[4], redM[4];
    const int tid = threadIdx.x;
    if (tid < FDIM) {
        const int row = tid;
        const int pr = (row >> 5) * 16 + (row & 15);
        const int h = (row >> 4) & 1;
        rn[row] = rsqrtf(gram[(pr * FDIM + row) * 2 + h]);
    }
    __syncthreads();
    float s = 0.f;
    for (int i = tid; i < GRAM_ELEMS; i += 256) {
        const int h = i & 1;
        const int qq = i >> 1;
        const int col = qq & 127;
        const int pr = qq >> 7;
        const int row = (pr >> 4) * 32 + (pr & 15) + (h << 4);
        const float g = gram[i] * rn[row] * rn[col];
        if (row != col && g > TAU && g <= 1.0f) s += g;
    }
    float m = mse_part[tid] + mse_part[tid + 256];      // 512 entries
    for (int off = 32; off; off >>= 1) {
        s += __shfl_down(s, off);
        m += __shfl_down(m, off);
    }
    if ((tid & 63) == 0) { redS[tid >> 6] = s; redM[tid >> 6] = m; }
    __syncthreads();
    if (tid == 0)
        out[0] = (redM[0] + redM[1] + redM[2] + redM[3]) * (1.0f / 8192000.0f) +
                 ALPHA * (redS[0] + redS[1] + redS[2] + redS[3]);
}

extern "C" void kernel_launch(void* const* d_in, const int* in_sizes, int n_in,
                              void* d_out, int out_size, void* d_ws, size_t ws_size,
                              hipStream_t stream) {
    const float* output = (const float*)d_in[0];
    const float* target = (const float*)d_in[1];
    const float* conv   = (const float*)d_in[2];
    float* out = (float*)d_out;

    float* wsf            = (float*)d_ws;
    float* mse_part       = wsf;                         // 512 floats
    float* gram           = wsf + 512;                   // 16384 floats
    unsigned int* pp      = (unsigned int*)(wsf + 512 + GRAM_ELEMS); // 16.8 MB
    (void)ws_size;   // need ~16.9 MB; harness provides ~402 MB (round-5 profile)

    // all buffers fully written before read -> no memsets
    fused_kernel<<<NBLK, 256, 0, stream>>>(output, target, conv, mse_part, pp);
    reduce_kernel<<<NPAIRQ / 16, 256, 0, stream>>>(pp, gram);
    finalize_kernel<<<1, 256, 0, stream>>>(gram, mse_part, out);
}

// Round 7
// 60.879 us; speedup vs baseline: 1.0430x; 1.0430x over previous
//
#include <hip/hip_runtime.h>
#include <hip/hip_bf16.h>

// loss = mean((output-target)^2) + ALPHA * sum(masked cosine Gram of
// V[128][196608]), V[f][d] = conv_w[o][i][f][k], d=(site,k), site=(o,i).
//
// Round 7: round-5 skeleton + PINNED register prefetch. sched_barrier(0)
// right after each loadc stops the scheduler from sinking the 12 prefetch
// loads to their use (round-5 VGPR=132 proved they sank; depth-0 pipeline).
// bf16-pair partials (16.8 MB) + round-6 reduce/finalize (validated).

typedef __attribute__((ext_vector_type(8))) short bf16x8;   // 8 bf16 = 4 VGPR
typedef __attribute__((ext_vector_type(4))) float f32x4;

#define ALPHA 0.0005f
#define TAU 0.2f

#define FDIM 128
#define TSTRIDE 52          // tile row stride in dwords (48 data + 4 pad)
#define GRAM_NBLK 512
#define CHUNK_F4 3072       // 32 sites * 96 float4
#define GRAM_ELEMS 16384
#define NPAIRQ 8192         // packed u32 per partial tile
#define MSE_N4 2048000      // 8192*1000/4
#define MSE_NBLK 2048

// branchless RNE f32->bf16 pair pack
__device__ __forceinline__ unsigned int pack_bf2(float lo, float hi) {
    union { float f; unsigned int u; } a, b;
    a.f = lo; b.f = hi;
    unsigned int al = (a.u + 0x7fffu + ((a.u >> 16) & 1u)) >> 16;
    unsigned int bh = (b.u + 0x7fffu + ((b.u >> 16) & 1u)) & 0xffff0000u;
    return (al & 0xffffu) | bh;
}

// ---------------------------------------------------------------- MSE kernel
__global__ void __launch_bounds__(256) mse_kernel(
        const float* __restrict__ o, const float* __restrict__ t,
        float* __restrict__ mse_part) {
    __shared__ float red[4];
    const int tid = threadIdx.x;
    const float4* o4 = reinterpret_cast<const float4*>(o);
    const float4* t4 = reinterpret_cast<const float4*>(t);
    float s = 0.f;
    for (int i = blockIdx.x * 256 + tid; i < MSE_N4; i += MSE_NBLK * 256) {
        float4 a = o4[i], b = t4[i];
        float dx = a.x - b.x, dy = a.y - b.y, dz = a.z - b.z, dw = a.w - b.w;
        s += dx * dx + dy * dy + dz * dz + dw * dw;
    }
    for (int off = 32; off; off >>= 1) s += __shfl_down(s, off);
    if ((tid & 63) == 0) red[tid >> 6] = s;
    __syncthreads();
    if (tid == 0) mse_part[blockIdx.x] = red[0] + red[1] + red[2] + red[3];
}

// --------------------------------------------------------------- Gram pieces
__device__ __forceinline__ void loadc(const f32x4* __restrict__ src4,
                                      size_t base4, f32x4 (&R)[12]) {
#pragma unroll
    for (int it = 0; it < 6; ++it) {
        R[2 * it]     = src4[base4 + 16 * it];        // site 2p
        R[2 * it + 1] = src4[base4 + 96 + 16 * it];   // site 2p+1
    }
    // PIN: prefetch loads may not be moved below this point (rule 18 / T14).
    // Their s_waitcnt stays at the consumer -> they fly through the next
    // convert + barrier + MFMA phase.
    __builtin_amdgcn_sched_barrier(0);
}

__device__ __forceinline__ void convertc(const f32x4 (&R)[12],
                                         unsigned int* __restrict__ tb,
                                         int p, int q) {
#pragma unroll
    for (int it = 0; it < 6; ++it)
#pragma unroll
        for (int u = 0; u < 4; ++u) {
            const int idx = (q + 16 * it) * 4 + u;    // [0,384): f*3 + k
            const int f = idx / 3;                    // magic-mul div
            const int k = idx - 3 * f;
            tb[f * TSTRIDE + k * 16 + p] = pack_bf2(R[2 * it][u], R[2 * it + 1][u]);
        }
}

__device__ __forceinline__ void barrier_tile() {
    // drain own ds_writes, then raw barrier; NO vmcnt drain (prefetch loads
    // stay in flight across the barrier — they target registers, not LDS).
    asm volatile("s_waitcnt lgkmcnt(0)" ::: "memory");
    __builtin_amdgcn_sched_barrier(0);
    __builtin_amdgcn_s_barrier();
    __builtin_amdgcn_sched_barrier(0);
}

__device__ __forceinline__ void mfmaph(const unsigned short* __restrict__ tu,
                                       int wave, int colr, int hi8,
                                       f32x4 (&acc0)[8], f32x4 (&acc1)[8]) {
#pragma unroll
    for (int ks = 0; ks < 3; ++ks) {
        const int koff = ks * 32 + hi8;
        bf16x8 a0 = *reinterpret_cast<const bf16x8*>(
            &tu[(wave * 32 + colr) * (TSTRIDE * 2) + koff]);
        bf16x8 a1 = *reinterpret_cast<const bf16x8*>(
            &tu[(wave * 32 + 16 + colr) * (TSTRIDE * 2) + koff]);
#pragma unroll
        for (int cc = 0; cc < 8; ++cc) {
            bf16x8 b = *reinterpret_cast<const bf16x8*>(
                &tu[(cc * 16 + colr) * (TSTRIDE * 2) + koff]);
            acc0[cc] = __builtin_amdgcn_mfma_f32_16x16x32_bf16(a0, b, acc0[cc], 0, 0, 0);
            acc1[cc] = __builtin_amdgcn_mfma_f32_16x16x32_bf16(a1, b, acc1[cc], 0, 0, 0);
        }
    }
}

// 512 blocks x 256 thr, 2 blocks/CU (53.2 KB LDS). 4 chunks of 32 sites;
// pinned reg-staged prefetch (RA/RB ping-pong), double-buffered bf16 tile,
// 1 barrier per chunk, counted waits only.
__global__ void __launch_bounds__(256, 2) gram_kernel(
        const float* __restrict__ conv, unsigned int* __restrict__ pp) {
    __shared__ unsigned int tile[2][FDIM * TSTRIDE];   // 2 x 26.6 KB
    const int tid = threadIdx.x;
    const int lane = tid & 63;
    const int wave = tid >> 6;
    const int p = tid >> 4;                 // site pair 0..15
    const int q = tid & 15;                 // float4 sub-offset 0..15
    const int colr = lane & 15;
    const int hi8 = (lane >> 4) * 8;
    const unsigned short* t0u = reinterpret_cast<const unsigned short*>(tile[0]);
    const unsigned short* t1u = reinterpret_cast<const unsigned short*>(tile[1]);

    f32x4 acc0[8], acc1[8];
#pragma unroll
    for (int cc = 0; cc < 8; ++cc) { acc0[cc] = (f32x4)0.f; acc1[cc] = (f32x4)0.f; }

    const f32x4* src4 = reinterpret_cast<const f32x4*>(conv);
    const size_t cb = (size_t)blockIdx.x * (4 * CHUNK_F4) + (2 * p) * 96 + q;

    f32x4 RA[12], RB[12];
    loadc(src4, cb + 0 * CHUNK_F4, RA);               // chunk 0

    // chunk 0
    loadc(src4, cb + 1 * CHUNK_F4, RB);               // prefetch chunk 1 (pinned)
    convertc(RA, tile[0], p, q);
    barrier_tile();
    mfmaph(t0u, wave, colr, hi8, acc0, acc1);
    // chunk 1
    loadc(src4, cb + 2 * CHUNK_F4, RA);               // prefetch chunk 2 (pinned)
    convertc(RB, tile[1], p, q);
    barrier_tile();
    mfmaph(t1u, wave, colr, hi8, acc0, acc1);
    // chunk 2
    loadc(src4, cb + 3 * CHUNK_F4, RB);               // prefetch chunk 3 (pinned)
    convertc(RA, tile[0], p, q);
    barrier_tile();
    mfmaph(t0u, wave, colr, hi8, acc0, acc1);
    // chunk 3
    convertc(RB, tile[1], p, q);
    barrier_tile();
    mfmaph(t1u, wave, colr, hi8, acc0, acc1);

    // partial tile, bf16 pair-packed: u32[pr*128+col] = pack(G[r], G[r+16]),
    // r = (pr>>4)*32 + (pr&15)  [validated bit-exact in round 6]
    unsigned int* myp = pp + (size_t)blockIdx.x * NPAIRQ;
    const int rsub = (lane >> 4) << 2;
#pragma unroll
    for (int cc = 0; cc < 8; ++cc) {
        const int col = cc * 16 + colr;
#pragma unroll
        for (int j = 0; j < 4; ++j) {
            const int pr = wave * 16 + rsub + j;
            myp[pr * FDIM + col] = pack_bf2(acc0[cc][j], acc1[cc][j]);
        }
    }
}

// ------------------------------------------------- partial reduce (bf16 pairs)
// 512 blocks x 256 thr: block owns 16 packed columns; 16 slices of 32 tiles.
__global__ void __launch_bounds__(256) reduce_kernel(
        const unsigned int* __restrict__ pp, float* __restrict__ gram) {
    __shared__ float red[16][16][2];
    const int tid = threadIdx.x;
    const int u = tid & 15;
    const int s = tid >> 4;                 // 0..15
    const int qq = blockIdx.x * 16 + u;
    float lo = 0.f, hi = 0.f;
#pragma unroll 8
    for (int b = s * 32; b < s * 32 + 32; ++b) {
        const unsigned int v = pp[(size_t)b * NPAIRQ + qq];
        lo += __uint_as_float(v << 16);
        hi += __uint_as_float(v & 0xffff0000u);
    }
    red[s][u][0] = lo; red[s][u][1] = hi;
    __syncthreads();
    if (tid < 32) {
        const int u2 = tid >> 1, h = tid & 1;
        float x = 0.f;
#pragma unroll
        for (int s2 = 0; s2 < 16; ++s2) x += red[s2][u2][h];
        gram[(blockIdx.x * 16 + u2) * 2 + h] = x;
    }
}

// ------------------------------------------------------------ finalize
// gram layout: g = (pr*128+col)*2 + h, row = (pr>>4)*32 + (pr&15) + 16h
__global__ void __launch_bounds__(256) finalize_kernel(
        const float* __restrict__ gram, const float* __restrict__ mse_part,
        float* __restrict__ out) {
    __shared__ float rn[FDIM];
    __shared__ float redS[4], redM[4];
    const int tid = threadIdx.x;
    if (tid < FDIM) {
        const int row = tid;
        const int pr = (row >> 5) * 16 + (row & 15);
        const int h = (row >> 4) & 1;
        rn[row] = rsqrtf(gram[(pr * FDIM + row) * 2 + h]);
    }
    __syncthreads();
    float s = 0.f;
    for (int i = tid; i < GRAM_ELEMS; i += 256) {
        const int h = i & 1;
        const int qq = i >> 1;
        const int col = qq & 127;
        const int pr = qq >> 7;
        const int row = (pr >> 4) * 32 + (pr & 15) + (h << 4);
        const float g = gram[i] * rn[row] * rn[col];
        if (row != col && g > TAU && g <= 1.0f) s += g;
    }
    float m = 0.f;
#pragma unroll 8
    for (int j = 0; j < 8; ++j) m += mse_part[tid * 8 + j];   // 2048 entries
    for (int off = 32; off; off >>= 1) {
        s += __shfl_down(s, off);
        m += __shfl_down(m, off);
    }
    if ((tid & 63) == 0) { redS[tid >> 6] = s; redM[tid >> 6] = m; }
    __syncthreads();
    if (tid == 0)
        out[0] = (redM[0] + redM[1] + redM[2] + redM[3]) * (1.0f / 8192000.0f) +
                 ALPHA * (redS[0] + redS[1] + redS[2] + redS[3]);
}

extern "C" void kernel_launch(void* const* d_in, const int* in_sizes, int n_in,
                              void* d_out, int out_size, void* d_ws, size_t ws_size,
                              hipStream_t stream) {
    const float* output = (const float*)d_in[0];
    const float* target = (const float*)d_in[1];
    const float* conv   = (const float*)d_in[2];
    float* out = (float*)d_out;

    float* wsf       = (float*)d_ws;
    float* mse_part  = wsf;                              // 2048 floats
    float* gram      = wsf + MSE_NBLK;                   // 16384 floats
    unsigned int* pp = (unsigned int*)(wsf + MSE_NBLK + GRAM_ELEMS); // 16.8 MB
    (void)ws_size;   // need ~16.9 MB; harness provides ~402 MB (round-5 profile)

    // all buffers fully written before read -> no memsets
    gram_kernel<<<GRAM_NBLK, 256, 0, stream>>>(conv, pp);
    mse_kernel<<<MSE_NBLK, 256, 0, stream>>>(output, target, mse_part);
    reduce_kernel<<<NPAIRQ / 16, 256, 0, stream>>>(pp, gram);
    finalize_kernel<<<1, 256, 0, stream>>>(gram, mse_part, out);
}

// Round 8
// 57.939 us; speedup vs baseline: 1.0959x; 1.0507x over previous
//
#include <hip/hip_runtime.h>
#include <hip/hip_bf16.h>

// loss = mean((output-target)^2) + ALPHA * sum(masked cosine Gram of
// V[128][196608]), V[f][d] = conv_w[o][i][f][k], d=(site,k), site=(o,i).
//
// Round 8: barrier-free Gram. One wave owns the FULL 128x128 tile (acc
// 256 VGPR, launch_bounds(256,1)); each wave streams its own contiguous
// conv range, loading MFMA fragments DIRECTLY from global (float3 per lane,
// 192B-contiguous 16-lane groups), converting in-register. K is enumerated
// in site-octets: 32-slot K-step = 4 lane-groups x (2 sites x 3k + 2 zero
// slots). Zero slots are exact no-ops. No LDS staging, no hot-loop barriers;
// depth-1 octet prefetch keeps ~12KB/wave in flight continuously.
// Epilogue: per-wave bf16-pair pack into LDS quarters (parallel), block sum
// -> 8MB partials. MSE fused as leading phase. reduce/finalize layouts are
// the round-6/7 validated ones.

typedef __attribute__((ext_vector_type(8))) short bf16x8;   // 8 bf16 = 4 VGPR
typedef __attribute__((ext_vector_type(4))) float f32x4;

#define ALPHA 0.0005f
#define TAU 0.2f

#define FDIM 128
#define NBLK 256            // 1 block/CU
#define GRAM_ELEMS 16384
#define NPAIRQ 8192         // packed u32 per partial tile
#define MSE_N4 2048000      // 8192*1000/4
#define NTILES 256          // partial tiles (1 per block)

// branchless RNE f32->bf16 pair pack
__device__ __forceinline__ unsigned int pack_bf2(float lo, float hi) {
    union { float f; unsigned int u; } a, b;
    a.f = lo; b.f = hi;
    unsigned int al = (a.u + 0x7fffu + ((a.u >> 16) & 1u)) >> 16;
    unsigned int bh = (b.u + 0x7fffu + ((b.u >> 16) & 1u)) & 0xffff0000u;
    return (al & 0xffffu) | bh;
}

// fragment: [a.x a.y a.z b.x b.y b.z 0 0] -> K-slots g*8+0..7 (6 used)
__device__ __forceinline__ bf16x8 make_frag(const float3& a, const float3& b) {
    union { bf16x8 v; unsigned int u[4]; } r;
    r.u[0] = pack_bf2(a.x, a.y);
    r.u[1] = pack_bf2(a.z, b.x);
    r.u[2] = pack_bf2(b.y, b.z);
    r.u[3] = 0;
    return r.v;
}

// load one octet's fragments for this lane: 8 row-tiles x 2 site-parities.
// lp = conv + W*24576 + (2*(lane>>4))*384 + (lane&15)*3 (+3072 per octet).
__device__ __forceinline__ void load_oct(const float* __restrict__ lp,
                                         float3 (&L)[8][2]) {
#pragma unroll
    for (int tt = 0; tt < 8; ++tt)
#pragma unroll
        for (int e = 0; e < 2; ++e)
            L[tt][e] = *reinterpret_cast<const float3*>(lp + tt * 48 + e * 384);
    __builtin_amdgcn_sched_barrier(0);      // pin prefetch at issue point
}

// consume one octet: build 8 frags, 64 MFMA (frag serves both A and B).
__device__ __forceinline__ void step_oct(const float3 (&L)[8][2],
                                         f32x4 (&acc)[8][8]) {
    bf16x8 fr[8];
#pragma unroll
    for (int tt = 0; tt < 8; ++tt) fr[tt] = make_frag(L[tt][0], L[tt][1]);
#pragma unroll
    for (int r = 0; r < 8; ++r)
#pragma unroll
        for (int c = 0; c < 8; ++c)
            acc[r][c] = __builtin_amdgcn_mfma_f32_16x16x32_bf16(
                fr[r], fr[c], acc[r][c], 0, 0, 0);
}

// ------------------------------------------------- fused MSE + Gram kernel
__global__ void __launch_bounds__(256, 1) fused_kernel(
        const float* __restrict__ o, const float* __restrict__ t,
        const float* __restrict__ conv,
        float* __restrict__ mse_part, unsigned int* __restrict__ pp) {
    __shared__ unsigned int pk[4][NPAIRQ];      // 128 KB: per-wave packed tile
    __shared__ float red[4];
    const int tid = threadIdx.x;
    const int lane = tid & 63;
    const int wave = tid >> 6;
    const int g = lane >> 4;                    // lane group 0..3
    const int fl = lane & 15;

    // per-wave contiguous conv range: wave W covers octets [8W, 8W+8)
    const int W = blockIdx.x * 4 + wave;
    const float* lp = conv + (size_t)W * 24576 + (2 * g) * 384 + fl * 3;

    float3 L0[8][2], L1[8][2];
    load_oct(lp, L0);                           // octet 0 in flight during MSE

    // ---------------- phase 1: MSE (grid-stride, deep ILP) ----------------
    {
        const int gid = blockIdx.x * 256 + tid;
        const f32x4* o4 = reinterpret_cast<const f32x4*>(o);
        const f32x4* t4 = reinterpret_cast<const f32x4*>(t);
        float s = 0.f;
#pragma unroll 8
        for (int p = 0; p < 31; ++p) {
            const int i = gid + p * 65536;
            f32x4 a = o4[i], b = t4[i];
            f32x4 d = a - b;
            s += d[0]*d[0] + d[1]*d[1] + d[2]*d[2] + d[3]*d[3];
        }
        if (gid < MSE_N4 - 31 * 65536) {        // 16384 tail threads
            const int i = gid + 31 * 65536;
            f32x4 a = o4[i], b = t4[i];
            f32x4 d = a - b;
            s += d[0]*d[0] + d[1]*d[1] + d[2]*d[2] + d[3]*d[3];
        }
        for (int off = 32; off; off >>= 1) s += __shfl_down(s, off);
        if (lane == 0) red[wave] = s;
        __syncthreads();
        if (tid == 0) mse_part[blockIdx.x] = red[0] + red[1] + red[2] + red[3];
    }

    // ---------------- phase 2: Gram, barrier-free octet pipeline ----------
    f32x4 acc[8][8];
#pragma unroll
    for (int r = 0; r < 8; ++r)
#pragma unroll
        for (int c = 0; c < 8; ++c) acc[r][c] = (f32x4)0.f;

#pragma unroll
    for (int oo = 0; oo < 8; oo += 2) {
        load_oct(lp + (oo + 1) * 3072, L1);     // prefetch odd octet
        step_oct(L0, acc);
        if (oo + 2 < 8) load_oct(lp + (oo + 2) * 3072, L0);  // prefetch even
        step_oct(L1, acc);
    }

    // ---------------- epilogue: pack + block-sum -> partials --------------
    // per-wave pack (parallel, static reg indices): row = 32m + g*4 + j,
    // pr = m*16 + g*4 + j, col = 16c + fl; pair rows (row, row+16).
#pragma unroll
    for (int m = 0; m < 4; ++m)
#pragma unroll
        for (int c = 0; c < 8; ++c)
#pragma unroll
            for (int j = 0; j < 4; ++j)
                pk[wave][(m * 16 + g * 4 + j) * FDIM + c * 16 + fl] =
                    pack_bf2(acc[2 * m][c][j], acc[2 * m + 1][c][j]);
    __syncthreads();

    unsigned int* myp = pp + (size_t)blockIdx.x * NPAIRQ;
    for (int e = tid; e < NPAIRQ; e += 256) {   // 32 iters, coalesced
        float lo = 0.f, hi = 0.f;
#pragma unroll
        for (int w = 0; w < 4; ++w) {
            const unsigned int v = pk[w][e];
            lo += __uint_as_float(v << 16);
            hi += __uint_as_float(v & 0xffff0000u);
        }
        myp[e] = pack_bf2(lo, hi);
    }
}

// ------------------------------------------------- partial reduce (bf16 pairs)
// 512 blocks x 256 thr: block owns 16 packed columns; 16 slices of 16 tiles.
__global__ void __launch_bounds__(256) reduce_kernel(
        const unsigned int* __restrict__ pp, float* __restrict__ gram) {
    __shared__ float red[16][16][2];
    const int tid = threadIdx.x;
    const int u = tid & 15;
    const int s = tid >> 4;                 // 0..15
    const int qq = blockIdx.x * 16 + u;
    float lo = 0.f, hi = 0.f;
#pragma unroll 8
    for (int b = s * 16; b < s * 16 + 16; ++b) {
        const unsigned int v = pp[(size_t)b * NPAIRQ + qq];
        lo += __uint_as_float(v << 16);
        hi += __uint_as_float(v & 0xffff0000u);
    }
    red[s][u][0] = lo; red[s][u][1] = hi;
    __syncthreads();
    if (tid < 32) {
        const int u2 = tid >> 1, h = tid & 1;
        float x = 0.f;
#pragma unroll
        for (int s2 = 0; s2 < 16; ++s2) x += red[s2][u2][h];
        gram[(blockIdx.x * 16 + u2) * 2 + h] = x;
    }
}

// ------------------------------------------------------------ finalize
// gram layout: g = (pr*128+col)*2 + h, row = (pr>>4)*32 + (pr&15) + 16h
__global__ void __launch_bounds__(256) finalize_kernel(
        const float* __restrict__ gram, const float* __restrict__ mse_part,
        float* __restrict__ out) {
    __shared__ float rn[FDIM];
    __shared__ float redS[4], redM[4];
    const int tid = threadIdx.x;
    if (tid < FDIM) {
        const int row = tid;
        const int pr = (row >> 5) * 16 + (row & 15);
        const int h = (row >> 4) & 1;
        rn[row] = rsqrtf(gram[(pr * FDIM + row) * 2 + h]);
    }
    __syncthreads();
    float s = 0.f;
    for (int i = tid; i < GRAM_ELEMS; i += 256) {
        const int h = i & 1;
        const int qq = i >> 1;
        const int col = qq & 127;
        const int pr = qq >> 7;
        const int row = (pr >> 4) * 32 + (pr & 15) + (h << 4);
        const float g = gram[i] * rn[row] * rn[col];
        if (row != col && g > TAU && g <= 1.0f) s += g;
    }
    float m = mse_part[tid];                    // exactly 256 entries
    for (int off = 32; off; off >>= 1) {
        s += __shfl_down(s, off);
        m += __shfl_down(m, off);
    }
    if ((tid & 63) == 0) { redS[tid >> 6] = s; redM[tid >> 6] = m; }
    __syncthreads();
    if (tid == 0)
        out[0] = (redM[0] + redM[1] + redM[2] + redM[3]) * (1.0f / 8192000.0f) +
                 ALPHA * (redS[0] + redS[1] + redS[2] + redS[3]);
}

extern "C" void kernel_launch(void* const* d_in, const int* in_sizes, int n_in,
                              void* d_out, int out_size, void* d_ws, size_t ws_size,
                              hipStream_t stream) {
    const float* output = (const float*)d_in[0];
    const float* target = (const float*)d_in[1];
    const float* conv   = (const float*)d_in[2];
    float* out = (float*)d_out;

    float* wsf       = (float*)d_ws;
    float* mse_part  = wsf;                              // 256 floats
    float* gram      = wsf + 256;                        // 16384 floats
    unsigned int* pp = (unsigned int*)(wsf + 256 + GRAM_ELEMS); // 8 MB
    (void)ws_size;   // need ~8.5 MB; harness provides ~402 MB (round-5 profile)

    // all buffers fully written before read -> no memsets
    fused_kernel<<<NBLK, 256, 0, stream>>>(output, target, conv, mse_part, pp);
    reduce_kernel<<<NPAIRQ / 16, 256, 0, stream>>>(pp, gram);
    finalize_kernel<<<1, 256, 0, stream>>>(gram, mse_part, out);
}